// Round 1
// baseline (127.066 us; speedup 1.0000x reference)
//
#include <hip/hip_runtime.h>

// Problem constants
#define B_  64
#define L_  2048
#define C_  64
#define K_  8
#define F_  24
#define D_  32   // K_ + F_
#define H_  64

// Output layout (flat floats): x_aug [B*L*C] | prob [B*K] | intensity [B*K] | selected_idx [B]
#define XAUG_N   (B_ * L_ * C_)          // 8388608
#define PROB_OFF (XAUG_N)                // 8388608
#define INT_OFF  (PROB_OFF + B_ * K_)    // 8389120
#define SEL_OFF  (INT_OFF + B_ * K_)     // 8389632

__device__ __forceinline__ float softplus_f(float v) {
    // numerically-stable log1p(exp(v)) = max(v,0) + log1p(exp(-|v|))
    return fmaxf(v, 0.f) + log1pf(expf(-fabsf(v)));
}

// ---------------------------------------------------------------------------
// Kernel 1: both MLP heads + softmax + softplus + gumbel-softmax + argmax.
// 16 blocks x 256 threads; each block handles 4 batch rows; thread = (row, h).
// Emits per-batch transform descriptor (kind, p0, p1) into ws:
//   kind 0: y = p0*x + p1          (ops 0,1,2,3,5)
//   kind 1: y = p0*tanh(p1*x)      (op 4)
//   kind 2: y = p0*x + p1*sin(x)   (op 6)
//   kind 3: y = p0*x[flip L]       (op 7)
// ---------------------------------------------------------------------------
__global__ void __launch_bounds__(256) head_kernel(
    const float* __restrict__ prev_prob, const float* __restrict__ features,
    const float* __restrict__ gumbel,    const float* __restrict__ log_temp,
    const float* __restrict__ pW1, const float* __restrict__ pb1,
    const float* __restrict__ pW2, const float* __restrict__ pb2,
    const float* __restrict__ pW3, const float* __restrict__ pb3,
    const float* __restrict__ iW1, const float* __restrict__ ib1,
    const float* __restrict__ iW2, const float* __restrict__ ib2,
    const float* __restrict__ iW3, const float* __restrict__ ib3,
    float* __restrict__ out,  // d_out base
    float* __restrict__ ws)   // 4 floats per batch row
{
    const int bl = threadIdx.x >> 6;          // 0..3  (sub-row within block)
    const int h  = threadIdx.x & 63;          // 0..63 (hidden unit / lane)
    const int b  = (blockIdx.x << 2) + bl;    // batch row

    __shared__ float s_in[4][D_];
    __shared__ float s_a[4][H_];
    __shared__ float s_b[4][H_];
    __shared__ float s_log[4][2 * K_];        // [0..7]=prob logits, [8..15]=intensity logits

    if (h < K_)      s_in[bl][h] = prev_prob[b * K_ + h];
    else if (h < D_) s_in[bl][h] = features[b * F_ + (h - K_)];
    __syncthreads();

    // ---- prob MLP ----
    float acc = pb1[h];
    #pragma unroll
    for (int d = 0; d < D_; ++d) acc = fmaf(s_in[bl][d], pW1[d * H_ + h], acc);
    s_a[bl][h] = fmaxf(acc, 0.f);
    __syncthreads();

    acc = pb2[h];
    #pragma unroll
    for (int d = 0; d < H_; ++d) acc = fmaf(s_a[bl][d], pW2[d * H_ + h], acc);
    s_b[bl][h] = fmaxf(acc, 0.f);
    __syncthreads();

    if (h < K_) {
        acc = pb3[h];
        #pragma unroll
        for (int d = 0; d < H_; ++d) acc = fmaf(s_b[bl][d], pW3[d * K_ + h], acc);
        s_log[bl][h] = acc;
    }
    __syncthreads();

    // ---- intensity MLP (reuse s_a, s_b) ----
    acc = ib1[h];
    #pragma unroll
    for (int d = 0; d < D_; ++d) acc = fmaf(s_in[bl][d], iW1[d * H_ + h], acc);
    s_a[bl][h] = fmaxf(acc, 0.f);
    __syncthreads();

    acc = ib2[h];
    #pragma unroll
    for (int d = 0; d < H_; ++d) acc = fmaf(s_a[bl][d], iW2[d * H_ + h], acc);
    s_b[bl][h] = fmaxf(acc, 0.f);
    __syncthreads();

    if (h < K_) {
        acc = ib3[h];
        #pragma unroll
        for (int d = 0; d < H_; ++d) acc = fmaf(s_b[bl][d], iW3[d * K_ + h], acc);
        s_log[bl][K_ + h] = acc;
    }
    __syncthreads();

    // ---- per-batch finalize (one lane per row) ----
    if (h == 0) {
        float plog[K_], ilog[K_];
        #pragma unroll
        for (int k = 0; k < K_; ++k) { plog[k] = s_log[bl][k]; ilog[k] = s_log[bl][K_ + k]; }

        // prob = softmax(plog)
        float m = plog[0];
        #pragma unroll
        for (int k = 1; k < K_; ++k) m = fmaxf(m, plog[k]);
        float e[K_], se = 0.f;
        #pragma unroll
        for (int k = 0; k < K_; ++k) { e[k] = expf(plog[k] - m); se += e[k]; }
        #pragma unroll
        for (int k = 0; k < K_; ++k) out[PROB_OFF + b * K_ + k] = e[k] / se;

        // intensity = softplus(ilog)
        float inten[K_];
        #pragma unroll
        for (int k = 0; k < K_; ++k) {
            inten[k] = softplus_f(ilog[k]);
            out[INT_OFF + b * K_ + k] = inten[k];
        }

        // gumbel-softmax
        float tau = expf(log_temp[0]);
        tau = fminf(fmaxf(tau, 0.01f), 10.0f);
        float z[K_];
        float m2 = -3.4e38f;
        #pragma unroll
        for (int k = 0; k < K_; ++k) {
            z[k] = (plog[k] + gumbel[b * K_ + k]) / tau;
            m2 = fmaxf(m2, z[k]);
        }
        float se2 = 0.f;
        #pragma unroll
        for (int k = 0; k < K_; ++k) { z[k] = expf(z[k] - m2); se2 += z[k]; }
        int idx = 0; float best = z[0];
        #pragma unroll
        for (int k = 1; k < K_; ++k) { if (z[k] > best) { best = z[k]; idx = k; } }

        float ys  = best / se2;
        float sel = (1.0f + ys) - ys;  // matches reference's straight-through value exactly-ish
        out[SEL_OFF + b] = (float)idx;

        const float t = inten[idx];
        int kind; float p0, p1 = 0.f;
        switch (idx) {
            case 0: kind = 0; p0 = sel;                  break;            // identity
            case 1: kind = 0; p0 = sel * (1.f + t);      break;            // scale up
            case 2: kind = 0; p0 = sel; p1 = sel * t;    break;            // shift
            case 3: kind = 0; p0 = sel * (1.f - t);      break;            // scale down
            case 4: kind = 1; p0 = sel; p1 = 1.f + t;    break;            // tanh warp
            case 5: kind = 0; p0 = sel * expf(-t);       break;            // exp damping
            case 6: kind = 2; p0 = sel; p1 = sel * t;    break;            // sin perturb
            default: kind = 3; p0 = sel;                 break;            // time reversal
        }
        ws[b * 4 + 0] = (float)kind;
        ws[b * 4 + 1] = p0;
        ws[b * 4 + 2] = p1;
    }
}

// ---------------------------------------------------------------------------
// Kernel 2: apply the selected transform, streaming, float4-vectorized.
// Grid: 64 batches * 128 blocks; branch is block-uniform (one batch per slab).
// ---------------------------------------------------------------------------
__global__ void __launch_bounds__(256) apply_kernel(
    const float* __restrict__ x, const float* __restrict__ ws,
    float* __restrict__ out)
{
    const int b = blockIdx.x >> 7;                          // batch row
    const int v = ((blockIdx.x & 127) << 8) + threadIdx.x;  // float4 index in [0, 32768)

    const float4* xb = (const float4*)x + (size_t)b * (L_ * C_ / 4);
    float4*       ob = (float4*)out + (size_t)b * (L_ * C_ / 4);

    const int   kind = (int)ws[b * 4 + 0];
    const float p0   = ws[b * 4 + 1];
    const float p1   = ws[b * 4 + 2];

    float4 r;
    if (kind == 3) {
        // time reversal: out[l] = p0 * x[L-1-l]; C=64 -> 16 float4 per row
        const int l = v >> 4, c = v & 15;
        const float4 xv = xb[(L_ - 1 - l) * 16 + c];
        r.x = p0 * xv.x; r.y = p0 * xv.y; r.z = p0 * xv.z; r.w = p0 * xv.w;
    } else {
        const float4 xv = xb[v];
        if (kind == 0) {
            r.x = fmaf(p0, xv.x, p1);
            r.y = fmaf(p0, xv.y, p1);
            r.z = fmaf(p0, xv.z, p1);
            r.w = fmaf(p0, xv.w, p1);
        } else if (kind == 1) {
            r.x = p0 * tanhf(p1 * xv.x);
            r.y = p0 * tanhf(p1 * xv.y);
            r.z = p0 * tanhf(p1 * xv.z);
            r.w = p0 * tanhf(p1 * xv.w);
        } else {
            r.x = fmaf(p0, xv.x, p1 * sinf(xv.x));
            r.y = fmaf(p0, xv.y, p1 * sinf(xv.y));
            r.z = fmaf(p0, xv.z, p1 * sinf(xv.z));
            r.w = fmaf(p0, xv.w, p1 * sinf(xv.w));
        }
    }
    ob[v] = r;
}

extern "C" void kernel_launch(void* const* d_in, const int* in_sizes, int n_in,
                              void* d_out, int out_size, void* d_ws, size_t ws_size,
                              hipStream_t stream) {
    const float* x         = (const float*)d_in[0];
    const float* prev_prob = (const float*)d_in[1];
    const float* features  = (const float*)d_in[2];
    const float* gumbel    = (const float*)d_in[3];
    const float* log_temp  = (const float*)d_in[4];
    const float* pW1 = (const float*)d_in[5];
    const float* pb1 = (const float*)d_in[6];
    const float* pW2 = (const float*)d_in[7];
    const float* pb2 = (const float*)d_in[8];
    const float* pW3 = (const float*)d_in[9];
    const float* pb3 = (const float*)d_in[10];
    const float* iW1 = (const float*)d_in[11];
    const float* ib1 = (const float*)d_in[12];
    const float* iW2 = (const float*)d_in[13];
    const float* ib2 = (const float*)d_in[14];
    const float* iW3 = (const float*)d_in[15];
    const float* ib3 = (const float*)d_in[16];

    float* out = (float*)d_out;
    float* ws  = (float*)d_ws;  // 64 rows * 4 floats = 1 KiB

    hipLaunchKernelGGL(head_kernel, dim3(B_ / 4), dim3(256), 0, stream,
                       prev_prob, features, gumbel, log_temp,
                       pW1, pb1, pW2, pb2, pW3, pb3,
                       iW1, ib1, iW2, ib2, iW3, ib3,
                       out, ws);

    hipLaunchKernelGGL(apply_kernel, dim3(B_ * (L_ * C_ / 4 / 256)), dim3(256), 0, stream,
                       x, ws, out);
}